// Round 7
// baseline (248.292 us; speedup 1.0000x reference)
//
#include <hip/hip_runtime.h>
#include <stdint.h>

// vol[n,d,h,w] = sum_c L[n,c,h,w] * R[n,c,h,w-d], 0 if w<d
// N=4, C=128, H=160, W=320, D=48, fp32 in/out.
//
// Banded-GEMM, m97-style streaming + T4 COUNTED-VMCNT PIPELINE:
//  - 1280 blocks = (n,h) x 2 w-halves (minimal R halo), 640 thr / 10 waves;
//    wave wt owns w-tile [wb+16wt, +16).
//  - R staged f32 by global_load_lds width-16 (HBM->LDS DMA, no VGPR trip)
//    into linear [32 c][208 j] chunk buffers, double-buffered (53.2 KB).
//  - 4 K-chunks of 32 c. Per chunk: issue DMA(k+1)+L(k+1), then wait
//    vmcnt(11|10) — retires ONLY chunk k's own ops, leaving chunk k+1 in
//    flight ACROSS the raw s_barrier (no compiler vmcnt(0) drain). This is
//    the m218 counted-vs-drain0 lever; R5/R6 measured the drain variant at
//    a flat 1.5 TB/s. Barrier collectivizes: every wave verified its own
//    chunk-k contribution -> all of chunk k is in LDS.
//  - Second raw barrier after compute(k) preserves WAR on buf[k&1] vs
//    stage(k+2). sched_barrier(0) fences keep the scheduler from moving
//    loads across the counted waits (under-wait hazard, rule #18).
//  - Left-edge j<0: loads clamped; garbage only reaches d>w outputs, which
//    the epilogue overwrites with the reference's zero padding (d<=w mask).
//  - Epilogue transposes through LDS (reusing chunk buffers) -> float4
//    stores along w.

#define NN 4
#define CC 128
#define HH 160
#define WW 320
#define DD 48
#define HWs (HH * WW)
#define WB 160
#define RJ 208          // j-window floats per c-row: [wb-48, wb+160)
#define CK 32           // channels per chunk
#define CHF (CK * RJ)   // floats per chunk buffer = 6656
#define NTH 640
#define GRID 1280

typedef _Float16 h2 __attribute__((ext_vector_type(2)));
typedef _Float16 f16x8 __attribute__((ext_vector_type(8)));
typedef float f32x4 __attribute__((ext_vector_type(4)));
typedef __fp16 h2raw __attribute__((ext_vector_type(2)));

__device__ __forceinline__ h2 pack2(float a, float b) {
  union { h2raw r; h2 h; } u;
  u.r = __builtin_amdgcn_cvt_pkrtz(a, b);  // v_cvt_pkrtz_f16_f32
  return u.h;
}

__device__ __forceinline__ void gl_lds16(const float* g, float* l) {
  __builtin_amdgcn_global_load_lds(
      (const __attribute__((address_space(1))) uint32_t*)g,
      (__attribute__((address_space(3))) uint32_t*)l, 16, 0, 0);
}

__global__ __launch_bounds__(NTH, 8)
void corr_kernel(const float* __restrict__ L, const float* __restrict__ R,
                 float* __restrict__ out) {
  // 53,248 B: 2 chunk buffers; reused as epilogue scratch (10 x 960 f32).
  __shared__ __align__(16) float S[2 * CHF];

  const int tid = threadIdx.x;
  const int wt  = tid >> 6;   // wave id == w-tile 0..9
  const int ln  = tid & 63;
  const int i16 = ln & 15;    // frag m/n index
  const int g   = ln >> 4;    // k-group 0..3

  // XCD-chunked bijective swizzle (1280 = 8 x 160)
  const int raw = blockIdx.x;
  const int bid = (raw & 7) * (GRID / 8) + (raw >> 3);
  const int wsplit = bid & 1;
  const int rnh = bid >> 1;
  const int n = rnh / HH;
  const int h = rnh - n * HH;
  const int wb = wsplit * WB;

  const size_t base = (size_t)n * CC * HWs + (size_t)h * WW;
  const float* Rb = R + base;
  const float* Lb = L + base + wb + 16 * wt + i16;

  // ---- staging task decomposition: 1664 tasks/chunk = 32 c x 52 j-blocks.
  // thread t handles tasks t, t+640 (all threads) and t+1280 (waves 0..5).
  // LDS dest per lane = uniform base + lane*16B -> DMA-compatible
  // ([c][j] pitch 208 exactly).
  const int t0 = tid, t1 = tid + 640, t2 = tid + 1280;
  const int c0 = t0 / 52, v0 = t0 - 52 * c0;
  const int c1 = t1 / 52, v1 = t1 - 52 * c1;
  const int c2 = t2 / 52, v2 = t2 - 52 * c2;
  int col0 = wb - 48 + 4 * v0; if (col0 < 0) col0 = 0;  // clamp (see epilogue)
  int col1 = wb - 48 + 4 * v1; if (col1 < 0) col1 = 0;
  int col2 = wb - 48 + 4 * v2; if (col2 < 0) col2 = 0;
  const float* gp0 = Rb + (size_t)c0 * HWs + col0;
  const float* gp1 = Rb + (size_t)c1 * HWs + col1;
  const float* gp2 = Rb + (size_t)c2 * HWs + col2;

  float lv[2][8];

  // per-wave VMEM ops per chunk issue: waves 0..5 -> 3 gl_lds + 8 L = 11,
  // waves 6..9 -> 2 gl_lds + 8 L = 10. These are the counted-wait literals.
  auto stage = [&](int kk) {  // kk literal (unrolled callers)
    float* dst = S + (kk & 1) * CHF;
    const size_t coff = (size_t)(CK * kk) * HWs;
    gl_lds16(gp0 + coff, dst + 4 * t0);
    gl_lds16(gp1 + coff, dst + 4 * t1);
    if (wt < 6) gl_lds16(gp2 + coff, dst + 4 * t2);  // wave-uniform branch
  };
  auto lload = [&](int kk) {  // L chunk kk: c = 32kk + 4e + g
    const float* p = Lb + (size_t)(CK * kk) * HWs;
#pragma unroll
    for (int e = 0; e < 8; ++e)
      lv[kk & 1][e] = p[(size_t)(4 * e + g) * HWs];
  };

  // ---- prologue: issue chunk 0 (no wait yet)
  stage(0);
  lload(0);

  f32x4 acc[4];
#pragma unroll
  for (int q = 0; q < 4; ++q) acc[q] = (f32x4){0.f, 0.f, 0.f, 0.f};

  // ---- 4 chunks; chunk k+1 stays in flight across compute(k)'s barrier
#pragma unroll
  for (int k = 0; k < 4; ++k) {
    if (k < 3) { stage(k + 1); lload(k + 1); }

    __builtin_amdgcn_sched_barrier(0);  // pin issue order vs the counted wait
    if (k < 3) {
      // retire chunk k's own 11|10 ops; chunk k+1's 11|10 remain in flight
      if (wt < 6) asm volatile("s_waitcnt vmcnt(11)" ::: "memory");
      else        asm volatile("s_waitcnt vmcnt(10)" ::: "memory");
    } else {
      asm volatile("s_waitcnt vmcnt(0)" ::: "memory");  // last chunk: drain
    }
    __builtin_amdgcn_s_barrier();       // collectivize: chunk k fully in LDS
    __builtin_amdgcn_sched_barrier(0);

    // A frag: element e <-> c-local 4e+g; pack pairs (2j, 2j+1)
    union AU { f16x8 v; h2 h[4]; } A;
#pragma unroll
    for (int j = 0; j < 4; ++j)
      A.h[j] = pack2(lv[k & 1][2 * j], lv[k & 1][2 * j + 1]);

    const float* Bb = S + (k & 1) * CHF;
#pragma unroll
    for (int q = 0; q < 4; ++q) {
      const int s = 16 * (wt + q) + i16;  // j-window col, in [0, 208)
      union BU { f16x8 v; h2 h[4]; } B;
#pragma unroll
      for (int j = 0; j < 4; ++j)         // rows 8j+g, 8j+4+g: 2 lanes/bank
        B.h[j] = pack2(Bb[(8 * j + g) * RJ + s], Bb[(8 * j + 4 + g) * RJ + s]);
      acc[q] = __builtin_amdgcn_mfma_f32_16x16x32_f16(A.v, B.v, acc[q], 0, 0, 0);
    }

    __builtin_amdgcn_s_barrier();       // WAR: buf[k&1] reads done before
    __builtin_amdgcn_sched_barrier(0);  // stage(k+2) overwrites it
  }

  // ---- epilogue: lane holds D[m=4g+r][n=i16] -> w = wb+16wt+4g+r,
  // d = 48-16q+4g+r-i16 (disjoint exact cover of d in [0,48) over q).
  // d > w outputs are the reference's zero padding (and the only places
  // clamped-load garbage can land) -> store 0 there. Transpose through
  // LDS scratch (chunk buffers, all reads done) -> float4 stores along w.
  float* ep = S + wt * (DD * 20);
  const int wl = wb + 16 * wt;
#pragma unroll
  for (int q = 0; q < 4; ++q)
#pragma unroll
    for (int r = 0; r < 4; ++r) {
      const int m = 4 * g + r;
      const int d = 48 - 16 * q + m - i16;
      if (d >= 0 && d < DD) ep[d * 20 + m] = (d <= wl + m) ? acc[q][r] : 0.f;
    }
  // own-wave write->read; compiler inserts the lgkmcnt wait

  const int l4 = ln & 3;
  const int dr = ln >> 2;  // 0..15
  float* op = out + (size_t)n * DD * HWs + (size_t)h * WW + wl + 4 * l4;
#pragma unroll
  for (int rr = 0; rr < 3; ++rr) {
    const int d = 16 * rr + dr;
    *(float4*)&op[(size_t)d * HWs] = *(const float4*)&ep[d * 20 + 4 * l4];
  }
}

extern "C" void kernel_launch(void* const* d_in, const int* in_sizes, int n_in,
                              void* d_out, int out_size, void* d_ws, size_t ws_size,
                              hipStream_t stream) {
  const float* L = (const float*)d_in[0];
  const float* R = (const float*)d_in[1];
  float* out = (float*)d_out;
  corr_kernel<<<dim3(GRID), dim3(NTH), 0, stream>>>(L, R, out);
}

// Round 9
// 245.347 us; speedup vs baseline: 1.0120x; 1.0120x over previous
//
#include <hip/hip_runtime.h>
#include <stdint.h>

// vol[n,d,h,w] = sum_c L[n,c,h,w] * R[n,c,h,w-d], 0 if w<d
// N=4, C=128, H=160, W=320, D=48, fp32 in/out.
//
// MAX-TLP revision: many small blocks, tiny LDS, full wave pool.
//  - 3200 blocks = (n,h) x 5 w-splits of 64; 256 thr = 4 waves; wave wid
//    owns w-tile [wb+16wid, +16). 15.4 KB LDS -> 8 blocks/CU (thread-capped)
//    = 32 waves/CU theoretical; 8 independently-phased blocks per CU keep
//    memory continuously fed (the R0-R7 plateau tracked resident waves).
//  - R window [wb-48, wb+68) staged f32 via global_load_lds width-16 into
//    [16 c][116 j] chunks, double-buffered (2 x 7.4 KB). Pitch 116 makes
//    B-frag ds_read_b32 <=3-way bank-aliased.
//  - 8 K-chunks of 16 c; mfma_f32_16x16x16f16, 4 q-tiles/chunk; A (L)
//    direct global->reg (4 dw/chunk), packed f32->f16 at use.
//  - Edges: DMA cols clamped to [0,316]. Left-clamp garbage lands only at
//    j<0 <=> d>w outputs, overwritten with the reference's zero padding by
//    the epilogue d<=w mask; right-clamp slots (jw>=112) are never read.
//  - Epilogue transposes through per-wave LDS scratch (reusing chunk
//    buffers after the final barrier) -> float4 stores along w.

#define NN 4
#define CC 128
#define HH 160
#define WW 320
#define DD 48
#define HWs (HH * WW)
#define WQ 64          // w extent per block
#define WIN 116        // staged j-window floats: [wb-48, wb+68)
#define CK 16          // channels per chunk
#define CHF (CK * WIN) // floats per chunk buffer = 1856
#define NTH 256
#define GRID 3200      // 640 (n,h) x 5 w-splits

typedef _Float16 f16x4 __attribute__((ext_vector_type(4)));
typedef _Float16 h2 __attribute__((ext_vector_type(2)));
typedef float f32x4 __attribute__((ext_vector_type(4)));
typedef __fp16 h2raw __attribute__((ext_vector_type(2)));

__device__ __forceinline__ h2 pack2(float a, float b) {
  union { h2raw r; h2 h; } u;
  u.r = __builtin_amdgcn_cvt_pkrtz(a, b);  // v_cvt_pkrtz_f16_f32
  return u.h;
}

__device__ __forceinline__ void gl_lds16(const float* g, float* l) {
  __builtin_amdgcn_global_load_lds(
      (const __attribute__((address_space(1))) uint32_t*)g,
      (__attribute__((address_space(3))) uint32_t*)l, 16, 0, 0);
}

__global__ __launch_bounds__(NTH, 8)
void corr_kernel(const float* __restrict__ L, const float* __restrict__ R,
                 float* __restrict__ out) {
  // 15,360 B: 2 chunk buffers (3712 f) + headroom; epilogue scratch 4x960 f.
  __shared__ __align__(16) float S[3840];

  const int tid = threadIdx.x;
  const int wid = tid >> 6;   // wave id == w-tile 0..3
  const int ln  = tid & 63;
  const int i16 = ln & 15;    // frag m/n index
  const int g   = ln >> 4;    // k-group 0..3

  // XCD-chunked bijective swizzle (3200 = 8 x 400): consecutive bids
  // (adjacent w-splits/h of a row -> shared halo/L-lines) stay on one XCD.
  const int raw = blockIdx.x;
  const int bid = (raw & 7) * (GRID / 8) + (raw >> 3);

  const int rnh = bid / 5;    // (n,h)
  const int wq  = bid - 5 * rnh;
  const int n = rnh / HH;
  const int h = rnh - n * HH;
  const int wb = wq * WQ;

  const size_t base = (size_t)n * CC * HWs + (size_t)h * WW;
  const float* Rb = R + base;
  const float* Lb = L + base + wb + 16 * wid + i16;

  // ---- staging tasks: 464 = 16 c x 29 float4-positions; thread t handles
  // t and t+256 (t+256 < 464 -> tid < 208). LDS dest = linear 16 B per task
  // (wave-uniform base + lane*16) -> DMA-compatible, [c][116] pitch exact.
  const int t0 = tid, t1 = tid + NTH;
  const int c0 = t0 / 29, v0 = t0 - 29 * c0;
  const int c1 = t1 / 29, v1 = t1 - 29 * c1;
  int col0 = wb - 48 + 4 * v0;
  int col1 = wb - 48 + 4 * v1;
  if (col0 < 0) col0 = 0; if (col0 > WW - 4) col0 = WW - 4;  // clamp, see hdr
  if (col1 < 0) col1 = 0; if (col1 > WW - 4) col1 = WW - 4;
  const float* gp0 = Rb + (size_t)c0 * HWs + col0;
  const float* gp1 = Rb + (size_t)c1 * HWs + col1;

  float lv[2][4];

  auto stage = [&](int kk) {  // kk literal (unrolled callers)
    float* dst = S + (kk & 1) * CHF;
    const size_t coff = (size_t)(CK * kk) * HWs;
    gl_lds16(gp0 + coff, dst + 4 * t0);
    if (t1 < 464) gl_lds16(gp1 + coff, dst + 4 * t1);
  };
  auto lload = [&](int kk) {  // L chunk kk: c = 16kk + 4e + g
    const float* p = Lb + (size_t)(CK * kk) * HWs;
#pragma unroll
    for (int e = 0; e < 4; ++e)
      lv[kk & 1][e] = p[(size_t)(4 * e + g) * HWs];
  };

  // ---- prologue
  stage(0);
  lload(0);
  __syncthreads();

  f32x4 acc[4];
#pragma unroll
  for (int q = 0; q < 4; ++q) acc[q] = (f32x4){0.f, 0.f, 0.f, 0.f};

  // ---- 8 chunks; prefetch next while computing current
#pragma unroll
  for (int k = 0; k < 8; ++k) {
    if (k < 7) { stage(k + 1); lload(k + 1); }

    // A frag: elem e <-> c-local 4e+g (shared bijection with B -> exact dot)
    union AU { f16x4 v; h2 h[2]; } A;
    A.h[0] = pack2(lv[k & 1][0], lv[k & 1][1]);
    A.h[1] = pack2(lv[k & 1][2], lv[k & 1][3]);

    const float* Bb = S + (k & 1) * CHF;
#pragma unroll
    for (int q = 0; q < 4; ++q) {
      const int s = 16 * (wid + q) + i16;  // j-window col, in [0, 112)
      union BU { f16x4 v; h2 h[2]; } B;
      B.h[0] = pack2(Bb[(g) * WIN + s], Bb[(4 + g) * WIN + s]);
      B.h[1] = pack2(Bb[(8 + g) * WIN + s], Bb[(12 + g) * WIN + s]);
      acc[q] = __builtin_amdgcn_mfma_f32_16x16x16f16(A.v, B.v, acc[q], 0, 0, 0);
    }
    __syncthreads();  // chunk k reads done; buf (k&1) free for k+2
  }

  // ---- epilogue: lane holds D[m=4g+r][n=i16] -> w = wb+16wid+4g+r,
  // d = 48-16q+4g+r-i16 (disjoint exact cover of d in [0,48) over q).
  // d > w outputs are the reference's zero padding (and the only places
  // clamped-load garbage can land) -> store 0 there. Transpose through
  // LDS scratch (chunk buffers, post-barrier) -> float4 stores along w.
  float* ep = S + wid * (DD * 20);
  const int wl = wb + 16 * wid;
#pragma unroll
  for (int q = 0; q < 4; ++q)
#pragma unroll
    for (int r = 0; r < 4; ++r) {
      const int m = 4 * g + r;
      const int d = 48 - 16 * q + m - i16;
      if (d >= 0 && d < DD) ep[d * 20 + m] = (d <= wl + m) ? acc[q][r] : 0.f;
    }
  // own-wave write->read; compiler inserts the lgkmcnt wait

  const int l4 = ln & 3;
  const int dr = ln >> 2;  // 0..15
  float* op = out + (size_t)n * DD * HWs + (size_t)h * WW + wl + 4 * l4;
#pragma unroll
  for (int rr = 0; rr < 3; ++rr) {
    const int d = 16 * rr + dr;
    *(float4*)&op[(size_t)d * HWs] = *(const float4*)&ep[d * 20 + 4 * l4];
  }
}

extern "C" void kernel_launch(void* const* d_in, const int* in_sizes, int n_in,
                              void* d_out, int out_size, void* d_ws, size_t ws_size,
                              hipStream_t stream) {
  const float* L = (const float*)d_in[0];
  const float* R = (const float*)d_in[1];
  float* out = (float*)d_out;
  corr_kernel<<<dim3(GRID), dim3(NTH), 0, stream>>>(L, R, out);
}